// Round 12
// baseline (107.725 us; speedup 1.0000x reference)
//
#include <hip/hip_runtime.h>
#include <hip/hip_bf16.h>

#define T_DIM 4096
#define E_DIM 2048
#define D_DIM 256

typedef __attribute__((ext_vector_type(4))) float f32x4;
typedef __attribute__((ext_vector_type(16))) float f32x16;
typedef __attribute__((ext_vector_type(8))) short s16x8;

__device__ __forceinline__ unsigned short f2bf(float f) {
  unsigned int u = __float_as_uint(f);
  unsigned int r = (u + 0x7FFFu + ((u >> 16) & 1u)) >> 16;  // RNE
  return (unsigned short)r;
}
__device__ __forceinline__ float bf2f(unsigned short h) {
  return __uint_as_float(((unsigned int)h) << 16);
}

__device__ __forceinline__ f32x4 mfma16(s16x8 a, s16x8 b, f32x4 c) {
  return __builtin_amdgcn_mfma_f32_16x16x32_bf16(a, b, c, 0, 0, 0);
}
__device__ __forceinline__ f32x16 mfma32(s16x8 a, s16x8 b, f32x16 c) {
  return __builtin_amdgcn_mfma_f32_32x32x16_bf16(a, b, c, 0, 0, 0);
}

__device__ __forceinline__ void gload_lds16(const void* g, void* l) {
  __builtin_amdgcn_global_load_lds((const __attribute__((address_space(1))) void*)g,
                                   (__attribute__((address_space(3))) void*)l, 16, 0, 0);
}

// ---------------- fused fp32 -> bf16 convert (x, Wq, Wk, Wv in one dispatch) --
__global__ __launch_bounds__(256) void cvt_all(const float* __restrict__ x,
                                               const float* __restrict__ wq,
                                               const float* __restrict__ wk,
                                               const float* __restrict__ wv,
                                               unsigned short* __restrict__ xb,
                                               unsigned short* __restrict__ wb) {
  int blk = blockIdx.x;
  const float* src;
  unsigned short* dst;
  int rel;
  if (blk < 4096)      { src = x;  dst = xb;           rel = blk; }
  else if (blk < 4352) { src = wq; dst = wb;           rel = blk - 4096; }
  else if (blk < 4608) { src = wk; dst = wb + 524288;  rel = blk - 4352; }
  else                 { src = wv; dst = wb + 1048576; rel = blk - 4608; }
  int i = rel * 256 + threadIdx.x;
  float4 a = ((const float4*)src)[i * 2];
  float4 b = ((const float4*)src)[i * 2 + 1];
  uint4 o;
  o.x = (unsigned int)f2bf(a.x) | ((unsigned int)f2bf(a.y) << 16);
  o.y = (unsigned int)f2bf(a.z) | ((unsigned int)f2bf(a.w) << 16);
  o.z = (unsigned int)f2bf(b.x) | ((unsigned int)f2bf(b.y) << 16);
  o.w = (unsigned int)f2bf(b.z) | ((unsigned int)f2bf(b.w) << 16);
  ((uint4*)dst)[i] = o;
}

// ---------------- fused QKV projection GEMM: BM=128 BN=64 BK=64 (R7, unchanged)
__global__ __launch_bounds__(256, 3) void qkv_gemm(
    const unsigned short* __restrict__ xb, const unsigned short* __restrict__ wb,
    unsigned short* __restrict__ Qg, unsigned short* __restrict__ Kg,
    unsigned short* __restrict__ Vt) {
  __shared__ __align__(16) unsigned short Al[2][128 * 64];
  __shared__ __align__(16) unsigned short Bl[2][64 * 64];
  int tid = threadIdx.x, wid = tid >> 6, lane = tid & 63;
  int lr = lane & 15, lk = lane >> 4;
  int bi_ = (int)blockIdx.x;
  int xcd = bi_ & 7, kk = bi_ >> 3;
  int mb_ = (kk / 12) * 8 + xcd, nb_ = kk % 12;
  int bm0 = mb_ * 128, bn0 = nb_ * 64;
  int wm = (wid >> 1) * 64, wn = (wid & 1) * 32;

  f32x4 acc[4][2];
#pragma unroll
  for (int m = 0; m < 4; ++m)
#pragma unroll
    for (int n = 0; n < 2; ++n) acc[m][n] = (f32x4){0.f, 0.f, 0.f, 0.f};

#define STAGE_QKV(kt, buf)                                                              \
  {                                                                                     \
    int k0 = (kt)*64;                                                                   \
    _Pragma("unroll") for (int i2 = 0; i2 < 4; ++i2) {                                  \
      int ci = (wid * 4 + i2) * 64 + lane;                                              \
      int row = ci >> 3, cc = ci & 7;                                                   \
      gload_lds16(&xb[(size_t)(bm0 + row) * E_DIM + k0 + ((cc ^ (row & 7)) << 3)],      \
                  &Al[buf][(size_t)(wid * 4 + i2) * 512]);                              \
    }                                                                                   \
    _Pragma("unroll") for (int i2 = 0; i2 < 2; ++i2) {                                  \
      int ci = (wid * 2 + i2) * 64 + lane;                                              \
      int row = ci >> 3, cc = ci & 7;                                                   \
      gload_lds16(&wb[(size_t)(bn0 + row) * E_DIM + k0 + ((cc ^ (row & 7)) << 3)],      \
                  &Bl[buf][(size_t)(wid * 2 + i2) * 512]);                              \
    }                                                                                   \
  }

  STAGE_QKV(0, 0);
  for (int kt = 0; kt < 32; ++kt) {
    int cur = kt & 1;
    __builtin_amdgcn_s_barrier();
    if (kt + 1 < 32) {
      STAGE_QKV(kt + 1, cur ^ 1);
      asm volatile("s_waitcnt vmcnt(6)" ::: "memory");
    } else {
      asm volatile("s_waitcnt vmcnt(0)" ::: "memory");
    }
    __builtin_amdgcn_s_barrier();
    s16x8 af[2][4], bfr[2][2];
#pragma unroll
    for (int c = 0; c < 2; ++c) {
#pragma unroll
      for (int m = 0; m < 4; ++m)
        af[c][m] = *(const s16x8*)&Al[cur][(size_t)(wm + m * 16 + lr) * 64 +
                                           (((c * 4 + lk) ^ (lr & 7)) << 3)];
#pragma unroll
      for (int n = 0; n < 2; ++n)
        bfr[c][n] = *(const s16x8*)&Bl[cur][(size_t)(wn + n * 16 + lr) * 64 +
                                            (((c * 4 + lk) ^ (lr & 7)) << 3)];
    }
#pragma unroll
    for (int c = 0; c < 2; ++c)
#pragma unroll
      for (int m = 0; m < 4; ++m)
#pragma unroll
        for (int n = 0; n < 2; ++n) acc[m][n] = mfma16(af[c][m], bfr[c][n], acc[m][n]);
  }

#pragma unroll
  for (int m = 0; m < 4; ++m) {
    int grow = bm0 + wm + m * 16 + lk * 4;
#pragma unroll
    for (int n = 0; n < 2; ++n) {
      int gcol = bn0 + wn + n * 16 + lr;
      unsigned short h[4];
#pragma unroll
      for (int r = 0; r < 4; ++r) h[r] = f2bf(acc[m][n][r]);
      if (gcol < 256) {
#pragma unroll
        for (int r = 0; r < 4; ++r) Qg[(size_t)(grow + r) * D_DIM + gcol] = h[r];
      } else if (gcol < 512) {
#pragma unroll
        for (int r = 0; r < 4; ++r) Kg[(size_t)(grow + r) * D_DIM + gcol - 256] = h[r];
      } else {
        uint2 w;
        w.x = (unsigned int)h[0] | ((unsigned int)h[1] << 16);
        w.y = (unsigned int)h[2] | ((unsigned int)h[3] << 16);
        *(uint2*)&Vt[(size_t)(gcol - 512) * T_DIM + grow] = w;
      }
    }
  }
#undef STAGE_QKV
}

// ---------------- flash attention: 32x32x16 MFMA, IN-REGISTER softmax ---------
// block j = t*(t+1)/2 + s (t 0..31, s 0..t); kv32 tiles {4s..4s+3}, 4 iters.
// 4 waves x 32q (128-q tile). Swapped QK^T: S^T = mfma32(K, Q) -> lane owns ONE
// q row (col = lane&31), 16 of 32 keys (other half in lane^32). Softmax lane-
// local: 1 shfl_xor(32) for max, 1 for sum, 8 packed-u32 swaps build PV's B.
// Swapped PV: O^T = mfma32(V^T, P^T) keeps O per-lane aligned with softmax.
// LDS ops per wave-tile: 16 K-reads + 16 V-reads (min bank occupancy), 0 other.
__global__ __launch_bounds__(256, 2) void attn_kernel(
    const unsigned short* __restrict__ Qg, const unsigned short* __restrict__ Kg,
    const unsigned short* __restrict__ Vt, unsigned short* __restrict__ Opart,
    float* __restrict__ mpart, float* __restrict__ lpart) {
  __shared__ __align__(16) unsigned short Kl[2][32 * 256];  // 2 x 16 KB
  __shared__ __align__(16) unsigned short Vl[2][256 * 32];  // 2 x 16 KB

  int bi = (int)blockIdx.x;
  int j = (bi & 7) * 66 + (bi >> 3);  // 528 = 8*66 bijective XCD remap
  int t = (int)((sqrtf(8.0f * (float)j + 1.0f) - 1.0f) * 0.5f);
  while (t > 0 && t * (t + 1) / 2 > j) --t;
  while ((t + 1) * (t + 2) / 2 <= j) ++t;
  int s = j - t * (t + 1) / 2;  // 0..t

  int tid = threadIdx.x, wid = tid >> 6, lane = tid & 63;
  int lo = lane & 31, hi = lane >> 5;
  int q0w = t * 128 + wid * 32;  // wave owns 32 q rows
  int myq = q0w + lo;
  int sw = lo & 7;                          // K-read swizzle
  int swv = (lo & 3) ^ ((lo >> 2) & 3);     // V-read swizzle

  // K tile 32x256el (32 granules/row): slot(row,g) holds src granule g^(row&7).
  // V^T tile 256x32el (4 granules/row): slot(d,g) holds src granule g^((d&3)^((d>>2)&3)).
#define STAGE_KV(jt, buf)                                                              \
  {                                                                                    \
    int kv_ = (jt)*32;                                                                 \
    _Pragma("unroll") for (int i2 = 0; i2 < 4; ++i2) {                                 \
      int ci = (wid * 4 + i2) * 64 + lane;                                             \
      int row = ci >> 5, g = ci & 31;                                                  \
      gload_lds16(&Kg[(size_t)(kv_ + row) * D_DIM + ((g ^ (row & 7)) << 3)],           \
                  &Kl[buf][(size_t)(wid * 4 + i2) * 512]);                             \
    }                                                                                  \
    _Pragma("unroll") for (int i2 = 0; i2 < 4; ++i2) {                                 \
      int ci = (wid * 4 + i2) * 64 + lane;                                             \
      int d_ = ci >> 2, g = ci & 3;                                                    \
      gload_lds16(&Vt[(size_t)d_ * T_DIM + kv_ + ((g ^ ((d_ & 3) ^ ((d_ >> 2) & 3))) << 3)], \
                  &Vl[buf][(size_t)(wid * 4 + i2) * 512]);                             \
    }                                                                                  \
  }

  STAGE_KV(4 * s, 0);  // prologue: 8 DMA/wave

  // Q fragments: lane holds Q[q0w+lo][c*16 + hi*8 .. +7]  (A/B 32x32x16 layout)
  s16x8 qf[16];  // 64 VGPR, persistent
#pragma unroll
  for (int c = 0; c < 16; ++c)
    qf[c] = *(const s16x8*)&Qg[(size_t)(q0w + lo) * D_DIM + c * 16 + hi * 8];

  float m_run = -1e30f, l_run = 0.f;
  f32x16 Oa[8];  // O^T[d = dg*32 + koff(r) + 4*hi][q = lo]
#pragma unroll
  for (int dg = 0; dg < 8; ++dg)
#pragma unroll
    for (int r = 0; r < 16; ++r) Oa[dg][r] = 0.f;
  const float scale = 0.0625f;  // 1/sqrt(256)

#pragma unroll 1
  for (int n = 0; n < 4; ++n) {
    int jt = 4 * s + n, kv = jt * 32, cur = n & 1;
    __builtin_amdgcn_s_barrier();  // all waves done reading buf[cur^1]
    if (n < 3) {
      STAGE_KV(jt + 1, cur ^ 1);
      // outstanding <= stage(n)(8) + [qf(16) at n==0] + stage(n+1)(8):
      // vmcnt(8) leaves only the 8 newest (stage n+1) in flight.
      asm volatile("s_waitcnt vmcnt(8)" ::: "memory");
    } else {
      asm volatile("s_waitcnt vmcnt(0)" ::: "memory");
    }
    __builtin_amdgcn_s_barrier();  // tile n visible block-wide
    const unsigned short* kl = &Kl[cur][0];
    const unsigned short* vl = &Vl[cur][0];

    // ---- QK^T: S^T[key x q]; lane: q = lo, keys = (r&3)+8*(r>>2)+4*hi ----
    f32x16 sa;
#pragma unroll
    for (int r = 0; r < 16; ++r) sa[r] = 0.f;
    __builtin_amdgcn_s_setprio(1);
#pragma unroll
    for (int c = 0; c < 16; ++c) {
      s16x8 kf = *(const s16x8*)&kl[(size_t)lo * 256 + (((2 * c + hi) ^ sw) << 3)];
      sa = mfma32(kf, qf[c], sa);
    }
    __builtin_amdgcn_s_setprio(0);

    // ---- scale + causal mask + in-register online softmax ----
    bool needmask = (kv + 31 > q0w);
    float tmax = -1e30f;
#pragma unroll
    for (int r = 0; r < 16; ++r) {
      float v = sa[r] * scale;
      int key = kv + (r & 3) + 8 * (r >> 2) + 4 * hi;
      if (needmask && key > myq) v = -1e30f;
      sa[r] = v;
      tmax = fmaxf(tmax, v);
    }
    tmax = fmaxf(tmax, __shfl_xor(tmax, 32));  // other 16 keys of same q
    float m_new = fmaxf(fmaxf(m_run, tmax), -1e29f);  // all-masked safe
    float alpha = __expf(m_run - m_new);
    float psum = 0.f;
#pragma unroll
    for (int r = 0; r < 16; ++r) {
      float p = __expf(sa[r] - m_new);
      sa[r] = p;
      psum += p;
    }
    psum += __shfl_xor(psum, 32);
    l_run = l_run * alpha + psum;
    m_run = m_new;

    // ---- build PV B-fragments (P^T) in-register: pack + half-swap ----
    unsigned o[8], so[8];
#pragma unroll
    for (int a = 0; a < 8; ++a) {
      o[a] = (unsigned)f2bf(sa[2 * a]) | ((unsigned)f2bf(sa[2 * a + 1]) << 16);
      so[a] = (unsigned)__shfl_xor((int)o[a], 32);
    }
    union { s16x8 v; unsigned u[4]; } b0, b1;
    b0.u[0] = hi ? so[2] : o[0];  b0.u[1] = hi ? so[3] : o[1];
    b0.u[2] = hi ? o[2] : so[0];  b0.u[3] = hi ? o[3] : so[1];
    b1.u[0] = hi ? so[6] : o[4];  b1.u[1] = hi ? so[7] : o[5];
    b1.u[2] = hi ? o[6] : so[4];  b1.u[3] = hi ? o[7] : so[5];

    // ---- rescale O (lane-local alpha; skip when no max growth) ----
    if (__any(alpha != 1.0f)) {
#pragma unroll
      for (int dg = 0; dg < 8; ++dg)
#pragma unroll
        for (int r = 0; r < 16; ++r) Oa[dg][r] *= alpha;
    }

    // ---- PV: O^T += mfma32(V^T, P^T) per 32-d group, 2 k-slices ----
    __builtin_amdgcn_s_setprio(1);
#pragma unroll
    for (int dg = 0; dg < 8; ++dg) {
      s16x8 vf0 = *(const s16x8*)&vl[(size_t)(dg * 32 + lo) * 32 + ((hi ^ swv) << 3)];
      Oa[dg] = mfma32(vf0, b0.v, Oa[dg]);
      s16x8 vf1 = *(const s16x8*)&vl[(size_t)(dg * 32 + lo) * 32 + (((2 + hi) ^ swv) << 3)];
      Oa[dg] = mfma32(vf1, b1.v, Oa[dg]);
    }
    __builtin_amdgcn_s_setprio(0);
  }

  // ---- store partials: Opart[j][256 d][128 q] bf16 ----
#pragma unroll
  for (int dg = 0; dg < 8; ++dg) {
#pragma unroll
    for (int r = 0; r < 16; ++r) {
      int d = dg * 32 + (r & 3) + 8 * (r >> 2) + 4 * hi;
      Opart[((size_t)j * 256 + d) * 128 + wid * 32 + lo] = f2bf(Oa[dg][r]);
    }
  }
  if (lane < 32) {
    mpart[(size_t)j * 128 + wid * 32 + lane] = m_run;
    lpart[(size_t)j * 128 + wid * 32 + lane] = l_run;
  }
#undef STAGE_KV
}

// ---------------- merge partials -> final output (R7, unchanged) --------------
__global__ __launch_bounds__(256) void merge_kernel(const unsigned short* __restrict__ Opart,
                                                    const float* __restrict__ mpart,
                                                    const float* __restrict__ lpart,
                                                    float* __restrict__ out) {
  __shared__ float trans[128 * 33];
  int blk = blockIdx.x;
  int t = blk >> 3, d0 = (blk & 7) * 32, q0 = t * 128;
  int ql = threadIdx.x & 127, dg = threadIdx.x >> 7;
  int base = t * (t + 1) / 2, np = t + 1;

  float M = -1e30f, den = 0.f;
  float acc[16];
#pragma unroll
  for (int k = 0; k < 16; ++k) acc[k] = 0.f;

#pragma unroll 1
  for (int p = 0; p < np; ++p) {
    float mp = mpart[(size_t)(base + p) * 128 + ql];
    float lp = lpart[(size_t)(base + p) * 128 + ql];
    float Mn = fmaxf(M, mp);
    float sc = __expf(M - Mn);
    float w = __expf(mp - Mn);
    den = den * sc + w * lp;
    const unsigned short* op = &Opart[((size_t)(base + p) * 256 + d0 + dg) * 128 + ql];
#pragma unroll
    for (int k = 0; k < 16; ++k) acc[k] = acc[k] * sc + w * bf2f(op[(size_t)(2 * k) * 128]);
    M = Mn;
  }
  float inv = 1.0f / den;
#pragma unroll
  for (int k = 0; k < 16; ++k) trans[ql * 33 + dg + 2 * k] = acc[k] * inv;
  __syncthreads();

#pragma unroll
  for (int k = 0; k < 16; ++k) {
    int q = (threadIdx.x >> 5) + 8 * k;
    int dd = threadIdx.x & 31;
    out[(size_t)(q0 + q) * 256 + d0 + dd] = trans[q * 33 + dd];
  }
}

// ---------------- host launch --------------------------------------------------
extern "C" void kernel_launch(void* const* d_in, const int* in_sizes, int n_in,
                              void* d_out, int out_size, void* d_ws, size_t ws_size,
                              hipStream_t stream) {
  const float* x  = (const float*)d_in[0];
  const float* Wq = (const float*)d_in[1];
  const float* Wk = (const float*)d_in[2];
  const float* Wv = (const float*)d_in[3];

  char* ws = (char*)d_ws;
  // workspace layout (bytes):
  //   xb    [4096][2048] bf16 : 16,777,216   @ 0
  //   wb    [768][2048]  bf16 :  3,145,728   @ 16,777,216
  //   Qg    [4096][256]  bf16 :  2,097,152   @ 19,922,944
  //   Kg    [4096][256]  bf16 :  2,097,152   @ 22,020,096
  //   Vt    [256][4096]  bf16 :  2,097,152   @ 24,117,248
  //   Opart [528][256][128] bf16: 34,603,008 @ 26,214,400
  //   mpart [528][128] f32    :    270,336   @ 60,817,408
  //   lpart [528][128] f32    :    270,336   @ 61,087,744   (total ~61.4 MB)
  unsigned short* xb = (unsigned short*)(ws);
  unsigned short* wb = (unsigned short*)(ws + 16777216);
  unsigned short* Qg = (unsigned short*)(ws + 19922944);
  unsigned short* Kg = (unsigned short*)(ws + 22020096);
  unsigned short* Vt = (unsigned short*)(ws + 24117248);
  unsigned short* Opart = (unsigned short*)(ws + 26214400);
  float* mpart = (float*)(ws + 60817408);
  float* lpart = (float*)(ws + 61087744);

  cvt_all<<<4864, 256, 0, stream>>>(x, Wq, Wk, Wv, xb, wb);
  qkv_gemm<<<384, 256, 0, stream>>>(xb, wb, Qg, Kg, Vt);
  attn_kernel<<<528, 256, 0, stream>>>(Qg, Kg, Vt, Opart, mpart, lpart);
  merge_kernel<<<256, 256, 0, stream>>>(Opart, mpart, lpart, (float*)d_out);
}

// Round 13
// 107.466 us; speedup vs baseline: 1.0024x; 1.0024x over previous
//
#include <hip/hip_runtime.h>
#include <hip/hip_bf16.h>

#define T_DIM 4096
#define E_DIM 2048
#define D_DIM 256

typedef __attribute__((ext_vector_type(4))) float f32x4;
typedef __attribute__((ext_vector_type(16))) float f32x16;
typedef __attribute__((ext_vector_type(8))) short s16x8;

__device__ __forceinline__ unsigned short f2bf(float f) {
  unsigned int u = __float_as_uint(f);
  unsigned int r = (u + 0x7FFFu + ((u >> 16) & 1u)) >> 16;  // RNE
  return (unsigned short)r;
}
__device__ __forceinline__ float bf2f(unsigned short h) {
  return __uint_as_float(((unsigned int)h) << 16);
}

__device__ __forceinline__ f32x4 mfma16(s16x8 a, s16x8 b, f32x4 c) {
  return __builtin_amdgcn_mfma_f32_16x16x32_bf16(a, b, c, 0, 0, 0);
}
__device__ __forceinline__ f32x16 mfma32(s16x8 a, s16x8 b, f32x16 c) {
  return __builtin_amdgcn_mfma_f32_32x32x16_bf16(a, b, c, 0, 0, 0);
}

__device__ __forceinline__ void gload_lds16(const void* g, void* l) {
  __builtin_amdgcn_global_load_lds((const __attribute__((address_space(1))) void*)g,
                                   (__attribute__((address_space(3))) void*)l, 16, 0, 0);
}

// ---------------- fused fp32 -> bf16 convert (x, Wq, Wk, Wv in one dispatch) --
__global__ __launch_bounds__(256) void cvt_all(const float* __restrict__ x,
                                               const float* __restrict__ wq,
                                               const float* __restrict__ wk,
                                               const float* __restrict__ wv,
                                               unsigned short* __restrict__ xb,
                                               unsigned short* __restrict__ wb) {
  int blk = blockIdx.x;
  const float* src;
  unsigned short* dst;
  int rel;
  if (blk < 4096)      { src = x;  dst = xb;           rel = blk; }
  else if (blk < 4352) { src = wq; dst = wb;           rel = blk - 4096; }
  else if (blk < 4608) { src = wk; dst = wb + 524288;  rel = blk - 4352; }
  else                 { src = wv; dst = wb + 1048576; rel = blk - 4608; }
  int i = rel * 256 + threadIdx.x;
  float4 a = ((const float4*)src)[i * 2];
  float4 b = ((const float4*)src)[i * 2 + 1];
  uint4 o;
  o.x = (unsigned int)f2bf(a.x) | ((unsigned int)f2bf(a.y) << 16);
  o.y = (unsigned int)f2bf(a.z) | ((unsigned int)f2bf(a.w) << 16);
  o.z = (unsigned int)f2bf(b.x) | ((unsigned int)f2bf(b.y) << 16);
  o.w = (unsigned int)f2bf(b.z) | ((unsigned int)f2bf(b.w) << 16);
  ((uint4*)dst)[i] = o;
}

// ---------------- fused QKV projection GEMM: BM=128 BN=64 BK=64 (R7, unchanged)
__global__ __launch_bounds__(256, 3) void qkv_gemm(
    const unsigned short* __restrict__ xb, const unsigned short* __restrict__ wb,
    unsigned short* __restrict__ Qg, unsigned short* __restrict__ Kg,
    unsigned short* __restrict__ Vt) {
  __shared__ __align__(16) unsigned short Al[2][128 * 64];
  __shared__ __align__(16) unsigned short Bl[2][64 * 64];
  int tid = threadIdx.x, wid = tid >> 6, lane = tid & 63;
  int lr = lane & 15, lk = lane >> 4;
  int bi_ = (int)blockIdx.x;
  int xcd = bi_ & 7, kk = bi_ >> 3;
  int mb_ = (kk / 12) * 8 + xcd, nb_ = kk % 12;
  int bm0 = mb_ * 128, bn0 = nb_ * 64;
  int wm = (wid >> 1) * 64, wn = (wid & 1) * 32;

  f32x4 acc[4][2];
#pragma unroll
  for (int m = 0; m < 4; ++m)
#pragma unroll
    for (int n = 0; n < 2; ++n) acc[m][n] = (f32x4){0.f, 0.f, 0.f, 0.f};

#define STAGE_QKV(kt, buf)                                                              \
  {                                                                                     \
    int k0 = (kt)*64;                                                                   \
    _Pragma("unroll") for (int i2 = 0; i2 < 4; ++i2) {                                  \
      int ci = (wid * 4 + i2) * 64 + lane;                                              \
      int row = ci >> 3, cc = ci & 7;                                                   \
      gload_lds16(&xb[(size_t)(bm0 + row) * E_DIM + k0 + ((cc ^ (row & 7)) << 3)],      \
                  &Al[buf][(size_t)(wid * 4 + i2) * 512]);                              \
    }                                                                                   \
    _Pragma("unroll") for (int i2 = 0; i2 < 2; ++i2) {                                  \
      int ci = (wid * 2 + i2) * 64 + lane;                                              \
      int row = ci >> 3, cc = ci & 7;                                                   \
      gload_lds16(&wb[(size_t)(bn0 + row) * E_DIM + k0 + ((cc ^ (row & 7)) << 3)],      \
                  &Bl[buf][(size_t)(wid * 2 + i2) * 512]);                              \
    }                                                                                   \
  }

  STAGE_QKV(0, 0);
  for (int kt = 0; kt < 32; ++kt) {
    int cur = kt & 1;
    __builtin_amdgcn_s_barrier();
    if (kt + 1 < 32) {
      STAGE_QKV(kt + 1, cur ^ 1);
      asm volatile("s_waitcnt vmcnt(6)" ::: "memory");
    } else {
      asm volatile("s_waitcnt vmcnt(0)" ::: "memory");
    }
    __builtin_amdgcn_s_barrier();
    s16x8 af[2][4], bfr[2][2];
#pragma unroll
    for (int c = 0; c < 2; ++c) {
#pragma unroll
      for (int m = 0; m < 4; ++m)
        af[c][m] = *(const s16x8*)&Al[cur][(size_t)(wm + m * 16 + lr) * 64 +
                                           (((c * 4 + lk) ^ (lr & 7)) << 3)];
#pragma unroll
      for (int n = 0; n < 2; ++n)
        bfr[c][n] = *(const s16x8*)&Bl[cur][(size_t)(wn + n * 16 + lr) * 64 +
                                            (((c * 4 + lk) ^ (lr & 7)) << 3)];
    }
#pragma unroll
    for (int c = 0; c < 2; ++c)
#pragma unroll
      for (int m = 0; m < 4; ++m)
#pragma unroll
        for (int n = 0; n < 2; ++n) acc[m][n] = mfma16(af[c][m], bfr[c][n], acc[m][n]);
  }

#pragma unroll
  for (int m = 0; m < 4; ++m) {
    int grow = bm0 + wm + m * 16 + lk * 4;
#pragma unroll
    for (int n = 0; n < 2; ++n) {
      int gcol = bn0 + wn + n * 16 + lr;
      unsigned short h[4];
#pragma unroll
      for (int r = 0; r < 4; ++r) h[r] = f2bf(acc[m][n][r]);
      if (gcol < 256) {
#pragma unroll
        for (int r = 0; r < 4; ++r) Qg[(size_t)(grow + r) * D_DIM + gcol] = h[r];
      } else if (gcol < 512) {
#pragma unroll
        for (int r = 0; r < 4; ++r) Kg[(size_t)(grow + r) * D_DIM + gcol - 256] = h[r];
      } else {
        uint2 w;
        w.x = (unsigned int)h[0] | ((unsigned int)h[1] << 16);
        w.y = (unsigned int)h[2] | ((unsigned int)h[3] << 16);
        *(uint2*)&Vt[(size_t)(gcol - 512) * T_DIM + grow] = w;
      }
    }
  }
#undef STAGE_QKV
}

// ---------------- flash attention: 32x32x16 MFMA, IN-REGISTER softmax ---------
// block j = t*(t+1)/2 + s (t 0..31, s 0..t); kv32 tiles {4s..4s+3}, 4 iters.
// 4 waves x 32q (128-q tile). Swapped QK^T: S^T = mfma32(K, Q) -> lane owns ONE
// q row (col = lane&31), 16 of 32 keys (other half in lane^32). Softmax lane-
// local: 1 shfl_xor(32) for max, 1 for sum, 8 packed-u32 swaps build PV's B.
// Swapped PV: O^T = mfma32(V^T, P^T) keeps O per-lane aligned with softmax.
// LDS ops per wave-tile: 16 K-reads + 16 V-reads (min bank occupancy), 0 other.
__global__ __launch_bounds__(256, 2) void attn_kernel(
    const unsigned short* __restrict__ Qg, const unsigned short* __restrict__ Kg,
    const unsigned short* __restrict__ Vt, unsigned short* __restrict__ Opart,
    float* __restrict__ mpart, float* __restrict__ lpart) {
  __shared__ __align__(16) unsigned short Kl[2][32 * 256];  // 2 x 16 KB
  __shared__ __align__(16) unsigned short Vl[2][256 * 32];  // 2 x 16 KB

  int bi = (int)blockIdx.x;
  int j = (bi & 7) * 66 + (bi >> 3);  // 528 = 8*66 bijective XCD remap
  int t = (int)((sqrtf(8.0f * (float)j + 1.0f) - 1.0f) * 0.5f);
  while (t > 0 && t * (t + 1) / 2 > j) --t;
  while ((t + 1) * (t + 2) / 2 <= j) ++t;
  int s = j - t * (t + 1) / 2;  // 0..t

  int tid = threadIdx.x, wid = tid >> 6, lane = tid & 63;
  int lo = lane & 31, hi = lane >> 5;
  int q0w = t * 128 + wid * 32;  // wave owns 32 q rows
  int myq = q0w + lo;
  int sw = lo & 7;                          // K-read swizzle
  int swv = (lo & 3) ^ ((lo >> 2) & 3);     // V-read swizzle

  // K tile 32x256el (32 granules/row): slot(row,g) holds src granule g^(row&7).
  // V^T tile 256x32el (4 granules/row): slot(d,g) holds src granule g^((d&3)^((d>>2)&3)).
#define STAGE_KV(jt, buf)                                                              \
  {                                                                                    \
    int kv_ = (jt)*32;                                                                 \
    _Pragma("unroll") for (int i2 = 0; i2 < 4; ++i2) {                                 \
      int ci = (wid * 4 + i2) * 64 + lane;                                             \
      int row = ci >> 5, g = ci & 31;                                                  \
      gload_lds16(&Kg[(size_t)(kv_ + row) * D_DIM + ((g ^ (row & 7)) << 3)],           \
                  &Kl[buf][(size_t)(wid * 4 + i2) * 512]);                             \
    }                                                                                  \
    _Pragma("unroll") for (int i2 = 0; i2 < 4; ++i2) {                                 \
      int ci = (wid * 4 + i2) * 64 + lane;                                             \
      int d_ = ci >> 2, g = ci & 3;                                                    \
      gload_lds16(&Vt[(size_t)d_ * T_DIM + kv_ + ((g ^ ((d_ & 3) ^ ((d_ >> 2) & 3))) << 3)], \
                  &Vl[buf][(size_t)(wid * 4 + i2) * 512]);                             \
    }                                                                                  \
  }

  STAGE_KV(4 * s, 0);  // prologue: 8 DMA/wave

  // Q fragments: lane holds Q[q0w+lo][c*16 + hi*8 .. +7]  (A/B 32x32x16 layout)
  s16x8 qf[16];  // 64 VGPR, persistent
#pragma unroll
  for (int c = 0; c < 16; ++c)
    qf[c] = *(const s16x8*)&Qg[(size_t)(q0w + lo) * D_DIM + c * 16 + hi * 8];

  float m_run = -1e30f, l_run = 0.f;
  f32x16 Oa[8];  // O^T[d = dg*32 + koff(r) + 4*hi][q = lo]
#pragma unroll
  for (int dg = 0; dg < 8; ++dg)
#pragma unroll
    for (int r = 0; r < 16; ++r) Oa[dg][r] = 0.f;
  const float scale = 0.0625f;  // 1/sqrt(256)

#pragma unroll 1
  for (int n = 0; n < 4; ++n) {
    int jt = 4 * s + n, kv = jt * 32, cur = n & 1;
    __builtin_amdgcn_s_barrier();  // all waves done reading buf[cur^1]
    if (n < 3) {
      STAGE_KV(jt + 1, cur ^ 1);
      // outstanding <= stage(n)(8) + [qf(16) at n==0] + stage(n+1)(8):
      // vmcnt(8) leaves only the 8 newest (stage n+1) in flight.
      asm volatile("s_waitcnt vmcnt(8)" ::: "memory");
    } else {
      asm volatile("s_waitcnt vmcnt(0)" ::: "memory");
    }
    __builtin_amdgcn_s_barrier();  // tile n visible block-wide
    const unsigned short* kl = &Kl[cur][0];
    const unsigned short* vl = &Vl[cur][0];

    // ---- QK^T: S^T[key x q]; lane: q = lo, keys = (r&3)+8*(r>>2)+4*hi ----
    f32x16 sa;
#pragma unroll
    for (int r = 0; r < 16; ++r) sa[r] = 0.f;
    __builtin_amdgcn_s_setprio(1);
#pragma unroll
    for (int c = 0; c < 16; ++c) {
      s16x8 kf = *(const s16x8*)&kl[(size_t)lo * 256 + (((2 * c + hi) ^ sw) << 3)];
      sa = mfma32(kf, qf[c], sa);
    }
    __builtin_amdgcn_s_setprio(0);

    // ---- scale + causal mask + in-register online softmax ----
    bool needmask = (kv + 31 > q0w);
    float tmax = -1e30f;
#pragma unroll
    for (int r = 0; r < 16; ++r) {
      float v = sa[r] * scale;
      int key = kv + (r & 3) + 8 * (r >> 2) + 4 * hi;
      if (needmask && key > myq) v = -1e30f;
      sa[r] = v;
      tmax = fmaxf(tmax, v);
    }
    tmax = fmaxf(tmax, __shfl_xor(tmax, 32));  // other 16 keys of same q
    float m_new = fmaxf(fmaxf(m_run, tmax), -1e29f);  // all-masked safe
    float alpha = __expf(m_run - m_new);
    float psum = 0.f;
#pragma unroll
    for (int r = 0; r < 16; ++r) {
      float p = __expf(sa[r] - m_new);
      sa[r] = p;
      psum += p;
    }
    psum += __shfl_xor(psum, 32);
    l_run = l_run * alpha + psum;
    m_run = m_new;

    // ---- build PV B-fragments (P^T) in-register: pack + half-swap ----
    unsigned o[8], so[8];
#pragma unroll
    for (int a = 0; a < 8; ++a) {
      o[a] = (unsigned)f2bf(sa[2 * a]) | ((unsigned)f2bf(sa[2 * a + 1]) << 16);
      so[a] = (unsigned)__shfl_xor((int)o[a], 32);
    }
    union { s16x8 v; unsigned u[4]; } b0, b1;
    b0.u[0] = hi ? so[2] : o[0];  b0.u[1] = hi ? so[3] : o[1];
    b0.u[2] = hi ? o[2] : so[0];  b0.u[3] = hi ? o[3] : so[1];
    b1.u[0] = hi ? so[6] : o[4];  b1.u[1] = hi ? so[7] : o[5];
    b1.u[2] = hi ? o[6] : so[4];  b1.u[3] = hi ? o[7] : so[5];

    // ---- rescale O (lane-local alpha; skip when no max growth) ----
    if (__any(alpha != 1.0f)) {
#pragma unroll
      for (int dg = 0; dg < 8; ++dg)
#pragma unroll
        for (int r = 0; r < 16; ++r) Oa[dg][r] *= alpha;
    }

    // ---- PV: O^T += mfma32(V^T, P^T) per 32-d group, 2 k-slices ----
    __builtin_amdgcn_s_setprio(1);
#pragma unroll
    for (int dg = 0; dg < 8; ++dg) {
      s16x8 vf0 = *(const s16x8*)&vl[(size_t)(dg * 32 + lo) * 32 + ((hi ^ swv) << 3)];
      Oa[dg] = mfma32(vf0, b0.v, Oa[dg]);
      s16x8 vf1 = *(const s16x8*)&vl[(size_t)(dg * 32 + lo) * 32 + (((2 + hi) ^ swv) << 3)];
      Oa[dg] = mfma32(vf1, b1.v, Oa[dg]);
    }
    __builtin_amdgcn_s_setprio(0);
  }

  // ---- store partials: Opart[j][256 d][128 q] bf16 ----
#pragma unroll
  for (int dg = 0; dg < 8; ++dg) {
#pragma unroll
    for (int r = 0; r < 16; ++r) {
      int d = dg * 32 + (r & 3) + 8 * (r >> 2) + 4 * hi;
      Opart[((size_t)j * 256 + d) * 128 + wid * 32 + lo] = f2bf(Oa[dg][r]);
    }
  }
  if (lane < 32) {
    mpart[(size_t)j * 128 + wid * 32 + lane] = m_run;
    lpart[(size_t)j * 128 + wid * 32 + lane] = l_run;
  }
#undef STAGE_KV
}

// ---------------- merge partials -> final output (R7, unchanged) --------------
__global__ __launch_bounds__(256) void merge_kernel(const unsigned short* __restrict__ Opart,
                                                    const float* __restrict__ mpart,
                                                    const float* __restrict__ lpart,
                                                    float* __restrict__ out) {
  __shared__ float trans[128 * 33];
  int blk = blockIdx.x;
  int t = blk >> 3, d0 = (blk & 7) * 32, q0 = t * 128;
  int ql = threadIdx.x & 127, dg = threadIdx.x >> 7;
  int base = t * (t + 1) / 2, np = t + 1;

  float M = -1e30f, den = 0.f;
  float acc[16];
#pragma unroll
  for (int k = 0; k < 16; ++k) acc[k] = 0.f;

#pragma unroll 1
  for (int p = 0; p < np; ++p) {
    float mp = mpart[(size_t)(base + p) * 128 + ql];
    float lp = lpart[(size_t)(base + p) * 128 + ql];
    float Mn = fmaxf(M, mp);
    float sc = __expf(M - Mn);
    float w = __expf(mp - Mn);
    den = den * sc + w * lp;
    const unsigned short* op = &Opart[((size_t)(base + p) * 256 + d0 + dg) * 128 + ql];
#pragma unroll
    for (int k = 0; k < 16; ++k) acc[k] = acc[k] * sc + w * bf2f(op[(size_t)(2 * k) * 128]);
    M = Mn;
  }
  float inv = 1.0f / den;
#pragma unroll
  for (int k = 0; k < 16; ++k) trans[ql * 33 + dg + 2 * k] = acc[k] * inv;
  __syncthreads();

#pragma unroll
  for (int k = 0; k < 16; ++k) {
    int q = (threadIdx.x >> 5) + 8 * k;
    int dd = threadIdx.x & 31;
    out[(size_t)(q0 + q) * 256 + d0 + dd] = trans[q * 33 + dd];
  }
}

// ---------------- host launch --------------------------------------------------
extern "C" void kernel_launch(void* const* d_in, const int* in_sizes, int n_in,
                              void* d_out, int out_size, void* d_ws, size_t ws_size,
                              hipStream_t stream) {
  const float* x  = (const float*)d_in[0];
  const float* Wq = (const float*)d_in[1];
  const float* Wk = (const float*)d_in[2];
  const float* Wv = (const float*)d_in[3];

  char* ws = (char*)d_ws;
  // workspace layout (bytes):
  //   xb    [4096][2048] bf16 : 16,777,216   @ 0
  //   wb    [768][2048]  bf16 :  3,145,728   @ 16,777,216
  //   Qg    [4096][256]  bf16 :  2,097,152   @ 19,922,944
  //   Kg    [4096][256]  bf16 :  2,097,152   @ 22,020,096
  //   Vt    [256][4096]  bf16 :  2,097,152   @ 24,117,248
  //   Opart [528][256][128] bf16: 34,603,008 @ 26,214,400
  //   mpart [528][128] f32    :    270,336   @ 60,817,408
  //   lpart [528][128] f32    :    270,336   @ 61,087,744   (total ~61.4 MB)
  unsigned short* xb = (unsigned short*)(ws);
  unsigned short* wb = (unsigned short*)(ws + 16777216);
  unsigned short* Qg = (unsigned short*)(ws + 19922944);
  unsigned short* Kg = (unsigned short*)(ws + 22020096);
  unsigned short* Vt = (unsigned short*)(ws + 24117248);
  unsigned short* Opart = (unsigned short*)(ws + 26214400);
  float* mpart = (float*)(ws + 60817408);
  float* lpart = (float*)(ws + 61087744);

  cvt_all<<<4864, 256, 0, stream>>>(x, Wq, Wk, Wv, xb, wb);
  qkv_gemm<<<384, 256, 0, stream>>>(xb, wb, Qg, Kg, Vt);
  attn_kernel<<<528, 256, 0, stream>>>(Qg, Kg, Vt, Opart, mpart, lpart);
  merge_kernel<<<256, 256, 0, stream>>>(Opart, mpart, lpart, (float*)d_out);
}